// Round 1
// baseline (24.485 us; speedup 1.0000x reference)
//
#include <hip/hip_runtime.h>
#include <hip/hip_bf16.h>
#include <math.h>

// scores[s] = sum_d E[s,d] * h[d]; out[s] = sigmoid(scores[s])
// One 64-lane wave per row. d = 1024 floats = 256 float4; 64 lanes -> 4 iters.
__global__ void attn_matvec_sigmoid(const float* __restrict__ h,
                                    const float* __restrict__ E,
                                    float* __restrict__ out,
                                    int seq_len, int d) {
    const int waves_per_block = blockDim.x >> 6;
    const int wave = blockIdx.x * waves_per_block + (threadIdx.x >> 6);
    const int lane = threadIdx.x & 63;
    if (wave >= seq_len) return;

    const float4* __restrict__ row = reinterpret_cast<const float4*>(E + (size_t)wave * d);
    const float4* __restrict__ hv  = reinterpret_cast<const float4*>(h);

    const int nvec = d >> 2;  // 256
    float acc = 0.0f;
#pragma unroll 4
    for (int i = lane; i < nvec; i += 64) {
        float4 e = row[i];
        float4 hh = hv[i];   // 4 KiB vector, L1-resident after first touch
        acc += e.x * hh.x + e.y * hh.y + e.z * hh.z + e.w * hh.w;
    }

    // 64-lane butterfly reduction
#pragma unroll
    for (int off = 32; off > 0; off >>= 1)
        acc += __shfl_xor(acc, off, 64);

    if (lane == 0)
        out[wave] = 1.0f / (1.0f + __expf(-acc));
}

extern "C" void kernel_launch(void* const* d_in, const int* in_sizes, int n_in,
                              void* d_out, int out_size, void* d_ws, size_t ws_size,
                              hipStream_t stream) {
    const float* hidden = (const float*)d_in[0];           // [1024]
    const float* enc    = (const float*)d_in[1];           // [32768, 1024]
    float* out          = (float*)d_out;                   // [1,1,32768] flat = 32768

    const int d = in_sizes[0];            // 1024
    const int seq_len = out_size;         // 32768

    const int block = 256;                            // 4 waves/block
    const int waves_per_block = block / 64;
    const int grid = (seq_len + waves_per_block - 1) / waves_per_block;  // 8192

    attn_matvec_sigmoid<<<grid, block, 0, stream>>>(hidden, enc, out, seq_len, d);
}